// Round 8
// baseline (27563.434 us; speedup 1.0000x reference)
//
#include <hip/hip_runtime.h>

typedef unsigned short u16;
typedef unsigned int u32;
typedef short v8s __attribute__((ext_vector_type(8)));
typedef float f32x4 __attribute__((ext_vector_type(4)));

#define NB 128
#define NU 1024
#define NF 64
#define NT 256
#define NOUT 32
#define NBLK 256
#define AS 520  // LDS A row stride in u16: 512 + 8 pad
#define FSTRIDE 16  // flag padding: 16 u32 = 64 B (one cacheline per block)
#define GO_IDX (NBLK * FSTRIDE)

__device__ __forceinline__ u16 f2bf(float f) {
  union { float f; u32 u; } v; v.f = f;
  u32 x = v.u;
  return (u16)((x + 0x7fffu + ((x >> 16) & 1u)) >> 16);
}
__device__ __forceinline__ float bf2f(u16 u) {
  union { u32 u; float f; } v; v.u = ((u32)u) << 16;
  return v.f;
}

// Flag-based grid barrier: per-block padded arrival flags (no RMW contention),
// block 0 polls all 256 in parallel (1 thread : 1 block), then releases a
// go-flag. Monotone generation counter; bounded spins as escape hatches.
__device__ __forceinline__ void gbar(u32* bar, u32 gen, int bid, int tid) {
  u32* go = bar + GO_IDX;
  __threadfence();
  __syncthreads();
  if (tid == 0)
    __hip_atomic_store(&bar[bid * FSTRIDE], gen, __ATOMIC_RELEASE, __HIP_MEMORY_SCOPE_AGENT);
  if (bid == 0) {
    u32 spin = 0;
    while (__hip_atomic_load(&bar[tid * FSTRIDE], __ATOMIC_ACQUIRE, __HIP_MEMORY_SCOPE_AGENT) < gen) {
      if (++spin > 5000000u) break;  // escape hatch
    }
    __syncthreads();
    if (tid == 0)
      __hip_atomic_store(go, gen, __ATOMIC_RELEASE, __HIP_MEMORY_SCOPE_AGENT);
  } else {
    if (tid == 0) {
      u32 spin = 0;
      while (__hip_atomic_load(go, __ATOMIC_ACQUIRE, __HIP_MEMORY_SCOPE_AGENT) < gen) {
        if (++spin > 5000000u) break;  // escape hatch
      }
    }
    __syncthreads();
  }
  __threadfence();
}

__global__ void init_bar(u32* bar) {
  int i = blockIdx.x * 256 + threadIdx.x;
  if (i <= GO_IDX + FSTRIDE) bar[i] = 0;
}

// Pack [top(ktop x 4096); R(1024 x 4096)] into MFMA-B-fragment-major bf16 with
// gate-permuted columns: z' col (t*16 + q*4 + c) <- orig col (q*1024 + t*4 + c).
// Layout: [t(256)][chunk][s(2)][lane(64)][j(8)] ; 16B per (lane) line.
__global__ void pack_weights(const float* __restrict__ top, const float* __restrict__ R,
                             int ktop, int nchunk, u16* __restrict__ dst) {
  int line = blockIdx.x * 256 + threadIdx.x;
  int l = line & 63;
  int rest = line >> 6;
  int s = rest & 1; rest >>= 1;
  int kk = rest % nchunk;
  int t  = rest / nchunk;
  if (t >= 256) return;
  int kbase = kk * 64 + s * 32 + (l >> 4) * 8;
  int col = ((l >> 2) & 3) * 1024 + t * 4 + (l & 3);
  v8s o;
#pragma unroll
  for (int j = 0; j < 8; ++j) {
    int k = kbase + j;
    float v = (k < ktop) ? top[(size_t)k * 4096 + col]
                         : R[(size_t)(k - ktop) * 4096 + col];
    o[j] = (short)f2bf(v);
  }
  *(v8s*)(void*)(dst + (size_t)line * 8) = o;
}

struct P {
  const float* x;
  const u16 *packE, *packC, *packR;
  const float *bl, *bc, *br, *W1, *b1, *W2, *b2;
  u16 *h0, *h1, *hl0, *hl1, *hr0, *hr1, *pred;
  float *cE, *cL, *cR;
  float* out;
  u32* bar;
};

// ---- phased staging: all loads of a phase independent -> one latency ----
__device__ __forceinline__ void stage512(u16* Asb, int tid, int m0,
                                         const u16* src, int c0) {
#pragma unroll
  for (int i = 0; i < 8; ++i) {
    int idx = tid + i * 256;
    int ml = idx >> 6, e = idx & 63;
    v8s v = *(const v8s*)(const void*)(src + (size_t)(m0 + ml) * NU + c0 + e * 8);
    *(v8s*)(void*)(Asb + ml * AS + e * 8) = v;
  }
}
__device__ __forceinline__ void stage64(u16* Asb, int tid, int m0,
                                        const u16* src) {
#pragma unroll
  for (int i = 0; i < 4; ++i) {
    int idx = tid + i * 256;
    int ml = idx >> 5, dw = idx & 31;
    u32 v = *(const u32*)(const void*)(src + (size_t)(m0 + ml) * NF + dw * 2);
    *(u32*)(void*)(Asb + ml * AS + dw * 2) = v;
  }
}
__device__ __forceinline__ void stage_x64(u16* Asb, int tid, int m0,
                                          const float* x, int t) {
#pragma unroll
  for (int i = 0; i < 4; ++i) {
    int idx = tid + i * 256;
    int ml = idx >> 5, dw = idx & 31;
    const float* sp = x + ((size_t)(m0 + ml) * NT + t) * NF + dw * 2;
    u32 v = (u32)f2bf(sp[0]) | ((u32)f2bf(sp[1]) << 16);
    *(u32*)(void*)(Asb + ml * AS + dw * 2) = v;
  }
}

// One MFMA phase: A cols [0, n*32) from LDS, B chunks [base_i, base_i+n) from global.
__device__ __forceinline__ void mfma_phase(f32x4& acc0, f32x4& acc1,
                                           const u16* Asb, const u16* tb,
                                           int base_i, int n,
                                           int l15, int quad, int lane) {
#pragma unroll
  for (int j = 0; j < 16; ++j) {
    if (j >= n) break;
    v8s b  = *(const v8s*)(const void*)(tb + ((size_t)((base_i + j) * 64 + lane)) * 8);
    v8s a0 = *(const v8s*)(const void*)(Asb + l15 * AS + j * 32 + quad * 8);
    v8s a1 = *(const v8s*)(const void*)(Asb + (16 + l15) * AS + j * 32 + quad * 8);
    acc0 = __builtin_amdgcn_mfma_f32_16x16x32_bf16(a0, b, acc0, 0, 0, 0);
    acc1 = __builtin_amdgcn_mfma_f32_16x16x32_bf16(a1, b, acc1, 0, 0, 0);
  }
}

// gates tail: z -> LDS transpose -> sigmoid/tanh; c-state in GLOBAL
__device__ __forceinline__ void gates_store(float* zbuf, int w, int lane, int quad, int l15,
                                            int m0, int tblk,
                                            const f32x4& acc0, const f32x4& acc1,
                                            const float* bias, float* cst, u16* hout,
                                            bool czero) {
#pragma unroll
  for (int r = 0; r < 4; ++r) {
    zbuf[(w * 32 + quad * 4 + r) * 17 + l15]      = acc0[r];
    zbuf[(w * 32 + 16 + quad * 4 + r) * 17 + l15] = acc1[r];
  }
  __syncthreads();
#pragma unroll
  for (int rep = 0; rep < 2; ++rep) {
    int pp = lane + rep * 64;
    int ml = pp >> 2;
    int cc = pp & 3;
    int col = tblk * 4 + cc;
    int zr = (w * 32 + ml) * 17;
    float iv = zbuf[zr + 0 + cc]  + bias[col];
    float fv = zbuf[zr + 4 + cc]  + bias[1024 + col];
    float gv = zbuf[zr + 8 + cc]  + bias[2048 + col];
    float ov = zbuf[zr + 12 + cc] + bias[3072 + col];
    size_t gi = (size_t)(m0 + ml) * NU + col;
    float cold = czero ? 0.f : cst[gi];
    float si = 1.f / (1.f + __expf(-iv));
    float sf = 1.f / (1.f + __expf(-fv));
    float so = 1.f / (1.f + __expf(-ov));
    float e2g = __expf(2.f * gv);
    float tg  = (e2g - 1.f) / (e2g + 1.f);
    float cn  = sf * cold + si * tg;
    float e2c = __expf(2.f * cn);
    float tc  = (e2c - 1.f) / (e2c + 1.f);
    cst[gi] = cn;
    hout[gi] = f2bf(so * tc);
  }
}

// fused dense head + state copies
__device__ void denseF(const P& p, float* dloc,
                       int tid, int bid,
                       const u16* hsrc, int step, bool docopy) {
  if (bid < 128) {
    int m = bid;
    int j = tid >> 3, sub = tid & 7;
    float sum = 0.f;
    for (int kk = 0; kk < 128; ++kk) {
      int k = sub + kk * 8;
      sum += bf2f(hsrc[(size_t)m * NU + k]) * p.W1[k * 32 + j];
    }
    sum += __shfl_down(sum, 4, 8);
    sum += __shfl_down(sum, 2, 8);
    sum += __shfl_down(sum, 1, 8);
    if (sub == 0) dloc[j] = fmaxf(sum + p.b1[j], 0.f);
    __syncthreads();
    if (tid < 64) {
      int f = tid;
      float s2 = p.b2[f];
#pragma unroll
      for (int k = 0; k < 32; ++k) s2 += dloc[k] * p.W2[k * 64 + f];
      p.out[((size_t)m * NOUT + step) * NF + f] = s2;
      p.pred[m * NF + f] = f2bf(s2);
    }
  } else if (docopy) {
    int ci = (bid - 128) * 256 + tid;
    const u32* h0d = (const u32*)p.h0;
    const u32* cEd = (const u32*)p.cE;
    for (int i = ci; i < 393216; i += 32768) {
      if (i < 65536)        ((u32*)p.hl1)[i] = h0d[i];
      else if (i < 131072)  ((u32*)p.hr1)[i - 65536] = h0d[i - 65536];
      else if (i < 262144)  ((u32*)p.cL)[i - 131072] = cEd[i - 131072];
      else                  ((u32*)p.cR)[i - 262144] = cEd[i - 262144];
    }
  }
}

__global__ void __launch_bounds__(256) rnn_persist(P p) {
  __shared__ __align__(16) u16 Asb[32 * AS];   // 33,280 B
  __shared__ float zbuf[128 * 17];             //  8,704 B
  __shared__ float dloc[32];

  const int tid = threadIdx.x;
  const int bid = blockIdx.x;
  const int wgn = bid & 63;
  const int mg  = bid >> 6;
  const int m0  = mg * 32;
  const int w    = tid >> 6;
  const int lane = tid & 63;
  const int quad = lane >> 4;
  const int l15  = lane & 15;
  const int tblk = wgn * 4 + w;

  const u16* tbE = p.packE + (size_t)tblk * 17408;  // [x(2 units); h(32 units)]
  const u16* tbC = p.packC + (size_t)tblk * 17408;  // [pred(2); hl(32)]
  const u16* tbR = p.packR + (size_t)tblk * 32768;  // [hl(32); hr(32)]

  u32 bno = 0;

  // ---- encoder: 256 steps; phases: x(64) | h[0:512] | h[512:1024] ----
  for (int t = 0; t < NT; ++t) {
    const u16* hread = (t & 1) ? p.h1 : p.h0;
    u16* hwrite      = (t & 1) ? p.h0 : p.h1;
    f32x4 acc0 = {0.f, 0.f, 0.f, 0.f};
    f32x4 acc1 = {0.f, 0.f, 0.f, 0.f};
    stage_x64(Asb, tid, m0, p.x, t);
    __syncthreads();
    mfma_phase(acc0, acc1, Asb, tbE, 0, 2, l15, quad, lane);
    if (t > 0) {
      __syncthreads();
      stage512(Asb, tid, m0, hread, 0);
      __syncthreads();
      mfma_phase(acc0, acc1, Asb, tbE, 2, 16, l15, quad, lane);
      __syncthreads();
      stage512(Asb, tid, m0, hread, 512);
      __syncthreads();
      mfma_phase(acc0, acc1, Asb, tbE, 18, 16, l15, quad, lane);
    }
    gates_store(zbuf, w, lane, quad, l15, m0, tblk, acc0, acc1,
                p.bl, p.cE, hwrite, t == 0);
    ++bno; gbar(p.bar, bno, bid, tid);
  }
  // final encoder h in p.h0

  denseF(p, dloc, tid, bid, p.h0, 0, true);
  ++bno; gbar(p.bar, bno, bid, tid);

  // ---- autoregressive: 31 steps ----
  for (int s = 1; s < NOUT; ++s) {
    const u16* hlr = (s & 1) ? p.hl1 : p.hl0;
    u16*       hlw = (s & 1) ? p.hl0 : p.hl1;
    const u16* hrr = (s & 1) ? p.hr1 : p.hr0;
    u16*       hrw = (s & 1) ? p.hr0 : p.hr1;

    // lstm_cell: phases pred(64) | hl[0:512] | hl[512:1024]
    {
      f32x4 acc0 = {0.f, 0.f, 0.f, 0.f};
      f32x4 acc1 = {0.f, 0.f, 0.f, 0.f};
      stage64(Asb, tid, m0, p.pred);
      __syncthreads();
      mfma_phase(acc0, acc1, Asb, tbC, 0, 2, l15, quad, lane);
      __syncthreads();
      stage512(Asb, tid, m0, hlr, 0);
      __syncthreads();
      mfma_phase(acc0, acc1, Asb, tbC, 2, 16, l15, quad, lane);
      __syncthreads();
      stage512(Asb, tid, m0, hlr, 512);
      __syncthreads();
      mfma_phase(acc0, acc1, Asb, tbC, 18, 16, l15, quad, lane);
      gates_store(zbuf, w, lane, quad, l15, m0, tblk, acc0, acc1,
                  p.bc, p.cL, hlw, false);
    }
    ++bno; gbar(p.bar, bno, bid, tid);

    // rnn_cell: phases hl_new[0:512] | hl_new[512:] | hr[0:512] | hr[512:]
    {
      f32x4 acc0 = {0.f, 0.f, 0.f, 0.f};
      f32x4 acc1 = {0.f, 0.f, 0.f, 0.f};
#pragma unroll
      for (int ph = 0; ph < 4; ++ph) {
        const u16* src = (ph < 2) ? hlw : hrr;
        stage512(Asb, tid, m0, src, (ph & 1) * 512);
        __syncthreads();
        mfma_phase(acc0, acc1, Asb, tbR, ph * 16, 16, l15, quad, lane);
        __syncthreads();
      }
      gates_store(zbuf, w, lane, quad, l15, m0, tblk, acc0, acc1,
                  p.br, p.cR, hrw, false);
    }
    ++bno; gbar(p.bar, bno, bid, tid);

    denseF(p, dloc, tid, bid, hrw, s, false);
    ++bno; gbar(p.bar, bno, bid, tid);
  }
}

extern "C" void kernel_launch(void* const* d_in, const int* in_sizes, int n_in,
                              void* d_out, int out_size, void* d_ws, size_t ws_size,
                              hipStream_t stream) {
  const float* x  = (const float*)d_in[0];
  const float* Wl = (const float*)d_in[1];
  const float* Rl = (const float*)d_in[2];
  const float* bl = (const float*)d_in[3];
  const float* Wc = (const float*)d_in[4];
  const float* Rc = (const float*)d_in[5];
  const float* bc = (const float*)d_in[6];
  const float* Wr = (const float*)d_in[7];
  const float* Rr = (const float*)d_in[8];
  const float* br = (const float*)d_in[9];
  const float* W1 = (const float*)d_in[10];
  const float* b1 = (const float*)d_in[11];
  const float* W2 = (const float*)d_in[12];
  const float* b2 = (const float*)d_in[13];

  char* ws = (char*)d_ws;
  size_t off = 0;
  auto alloc = [&](size_t bytes) -> void* {
    void* r = ws + off;
    off += (bytes + 255) & ~(size_t)255;
    return r;
  };
  const size_t szPackE = (size_t)256 * 17408 * 2;  // 8,912,896
  const size_t szPackR = (size_t)256 * 32768 * 2;  // 16,777,216
  u16* packE = (u16*)alloc(szPackE);
  u16* packC = (u16*)alloc(szPackE);
  u16* packR = (u16*)alloc(szPackR);
  u16* h0  = (u16*)alloc(NB * NU * 2);
  u16* h1  = (u16*)alloc(NB * NU * 2);
  u16* hl0 = (u16*)alloc(NB * NU * 2);
  u16* hl1 = (u16*)alloc(NB * NU * 2);
  u16* hr0 = (u16*)alloc(NB * NU * 2);
  u16* hr1 = (u16*)alloc(NB * NU * 2);
  float* cE = (float*)alloc(NB * NU * 4);
  float* cL = (float*)alloc(NB * NU * 4);
  float* cR = (float*)alloc(NB * NU * 4);
  u16* pred = (u16*)alloc(NB * NF * 2);
  u32* bar  = (u32*)alloc((GO_IDX + FSTRIDE + 64) * 4);

  init_bar<<<dim3(17), dim3(256), 0, stream>>>(bar);
  pack_weights<<<dim3(128 * 17), dim3(256), 0, stream>>>(Wl, Rl, 64, 17, packE);
  pack_weights<<<dim3(128 * 17), dim3(256), 0, stream>>>(Wc, Rc, 64, 17, packC);
  pack_weights<<<dim3(128 * 32), dim3(256), 0, stream>>>(Wr, Rr, 1024, 32, packR);

  static P p;
  p.x = x;
  p.packE = packE; p.packC = packC; p.packR = packR;
  p.bl = bl; p.bc = bc; p.br = br;
  p.W1 = W1; p.b1 = b1; p.W2 = W2; p.b2 = b2;
  p.h0 = h0; p.h1 = h1; p.hl0 = hl0; p.hl1 = hl1; p.hr0 = hr0; p.hr1 = hr1;
  p.pred = pred;
  p.cE = cE; p.cL = cL; p.cR = cR;
  p.out = (float*)d_out;
  p.bar = bar;

  // Plain launch: barrier needs only co-residency (256 blocks on 256 CUs at
  // 42 KB LDS -> all resident; proven by rounds 3 & 7).
  rnn_persist<<<dim3(NBLK), dim3(256), 0, stream>>>(p);
}

// Round 9
// 5271.800 us; speedup vs baseline: 5.2285x; 5.2285x over previous
//
#include <hip/hip_runtime.h>

typedef unsigned short u16;
typedef unsigned int u32;
typedef unsigned long long u64;
typedef short v8s __attribute__((ext_vector_type(8)));
typedef float f32x4 __attribute__((ext_vector_type(4)));

#define NB 128
#define NU 1024
#define NF 64
#define NT 256
#define NOUT 32
#define NBLK 256
#define AS 520      // LDS A row stride in u16: 512 + 8 pad
#define FSTRIDE 32  // flag padding: 32 u32 = 128 B
#define GO_IDX (NBLK * FSTRIDE)

__device__ __forceinline__ u16 f2bf(float f) {
  union { float f; u32 u; } v; v.f = f;
  u32 x = v.u;
  return (u16)((x + 0x7fffu + ((x >> 16) & 1u)) >> 16);
}
__device__ __forceinline__ float bf2f(u16 u) {
  union { u32 u; float f; } v; v.u = ((u32)u) << 16;
  return v.f;
}

// --- coherent (agent-scope, fence-free) access helpers: sc-bit path ---
__device__ __forceinline__ u64 cload64(const u16* p) {
  return __hip_atomic_load((const u64*)(const void*)p, __ATOMIC_RELAXED,
                           __HIP_MEMORY_SCOPE_AGENT);
}
__device__ __forceinline__ void cstore64(u16* p, u64 v) {
  __hip_atomic_store((u64*)(void*)p, v, __ATOMIC_RELAXED, __HIP_MEMORY_SCOPE_AGENT);
}
__device__ __forceinline__ float cloadf(const float* p) {
  return __hip_atomic_load(p, __ATOMIC_RELAXED, __HIP_MEMORY_SCOPE_AGENT);
}
__device__ __forceinline__ void cstoref(float* p, float v) {
  __hip_atomic_store(p, v, __ATOMIC_RELAXED, __HIP_MEMORY_SCOPE_AGENT);
}

// Fence-free grid barrier: per-block padded arrival flags (relaxed agent
// atomics -> coherence point, no L2 sweeps). Ordering: s_waitcnt vmcnt(0)
// drains this wave's coherent data stores before flag store; consumer's
// in-order issue after flag observation guarantees fresh coherent loads.
__device__ __forceinline__ void gbar(u32* bar, u32 gen, int bid, int tid) {
  asm volatile("s_waitcnt vmcnt(0)" ::: "memory");
  __syncthreads();
  if (tid == 0)
    __hip_atomic_store(&bar[bid * FSTRIDE], gen, __ATOMIC_RELAXED, __HIP_MEMORY_SCOPE_AGENT);
  u32* go = bar + GO_IDX;
  if (bid == 0) {
    u32 spin = 0;
    while (__hip_atomic_load(&bar[tid * FSTRIDE], __ATOMIC_RELAXED, __HIP_MEMORY_SCOPE_AGENT) < gen) {
      if (++spin > 20000000u) break;  // escape hatch
    }
    __syncthreads();
    if (tid == 0)
      __hip_atomic_store(go, gen, __ATOMIC_RELAXED, __HIP_MEMORY_SCOPE_AGENT);
  } else {
    if (tid == 0) {
      u32 spin = 0;
      while (__hip_atomic_load(go, __ATOMIC_RELAXED, __HIP_MEMORY_SCOPE_AGENT) < gen) {
        if (++spin > 20000000u) break;  // escape hatch
      }
    }
    __syncthreads();
  }
  asm volatile("" ::: "memory");
}

__global__ void init_bar(u32* bar) {
  int i = blockIdx.x * 256 + threadIdx.x;
  if (i < GO_IDX + 64) bar[i] = 0;
}

// Pack [top(ktop x 4096); R(1024 x 4096)] into MFMA-B-fragment-major bf16 with
// gate-permuted columns: z' col (t*16 + q*4 + c) <- orig col (q*1024 + t*4 + c).
__global__ void pack_weights(const float* __restrict__ top, const float* __restrict__ R,
                             int ktop, int nchunk, u16* __restrict__ dst) {
  int line = blockIdx.x * 256 + threadIdx.x;
  int l = line & 63;
  int rest = line >> 6;
  int s = rest & 1; rest >>= 1;
  int kk = rest % nchunk;
  int t  = rest / nchunk;
  if (t >= 256) return;
  int kbase = kk * 64 + s * 32 + (l >> 4) * 8;
  int col = ((l >> 2) & 3) * 1024 + t * 4 + (l & 3);
  v8s o;
#pragma unroll
  for (int j = 0; j < 8; ++j) {
    int k = kbase + j;
    float v = (k < ktop) ? top[(size_t)k * 4096 + col]
                         : R[(size_t)(k - ktop) * 4096 + col];
    o[j] = (short)f2bf(v);
  }
  *(v8s*)(void*)(dst + (size_t)line * 8) = o;
}

struct P {
  const float* x;
  const u16 *packE, *packC, *packR;
  const float *bl, *bc, *br, *W1, *b1, *W2, *b2;
  u16 *h0, *h1, *hl0, *hl1, *hr0, *hr1;
  float* pred;   // fp32, coherent
  float *cE, *cL, *cR;
  float* out;
  u32* bar;
};

// ---- staging: coherent 8B loads, all independent -> one latency per phase ----
__device__ __forceinline__ void stage512(u16* Asb, int tid, int m0,
                                         const u16* src, int c0) {
#pragma unroll
  for (int i = 0; i < 8; ++i) {
    int idx = tid + i * 256;
    int ml = idx >> 6, e = idx & 63;
    const u16* sp = src + (size_t)(m0 + ml) * NU + c0 + e * 8;
    u64 a = cload64(sp);
    u64 b = cload64(sp + 4);
    union { u64 q[2]; v8s v; } u; u.q[0] = a; u.q[1] = b;
    *(v8s*)(void*)(Asb + ml * AS + e * 8) = u.v;
  }
}
__device__ __forceinline__ void stage64p(u16* Asb, int tid, int m0,
                                         const float* predf) {
#pragma unroll
  for (int i = 0; i < 4; ++i) {
    int idx = tid + i * 256;
    int ml = idx >> 5, dw = idx & 31;
    const float* sp = predf + (size_t)(m0 + ml) * NF + dw * 2;
    float f0 = cloadf(sp);
    float f1 = cloadf(sp + 1);
    u32 v = (u32)f2bf(f0) | ((u32)f2bf(f1) << 16);
    *(u32*)(void*)(Asb + ml * AS + dw * 2) = v;
  }
}
__device__ __forceinline__ void stage_x64(u16* Asb, int tid, int m0,
                                          const float* x, int t) {
#pragma unroll
  for (int i = 0; i < 4; ++i) {
    int idx = tid + i * 256;
    int ml = idx >> 5, dw = idx & 31;
    const float* sp = x + ((size_t)(m0 + ml) * NT + t) * NF + dw * 2;
    u32 v = (u32)f2bf(sp[0]) | ((u32)f2bf(sp[1]) << 16);
    *(u32*)(void*)(Asb + ml * AS + dw * 2) = v;
  }
}

// One MFMA phase: A from LDS, B chunks from global (plain, L2-resident).
__device__ __forceinline__ void mfma_phase(f32x4& acc0, f32x4& acc1,
                                           const u16* Asb, const u16* tb,
                                           int base_i, int n,
                                           int l15, int quad, int lane) {
#pragma unroll
  for (int j = 0; j < 16; ++j) {
    if (j >= n) break;
    v8s b  = *(const v8s*)(const void*)(tb + ((size_t)((base_i + j) * 64 + lane)) * 8);
    v8s a0 = *(const v8s*)(const void*)(Asb + l15 * AS + j * 32 + quad * 8);
    v8s a1 = *(const v8s*)(const void*)(Asb + (16 + l15) * AS + j * 32 + quad * 8);
    acc0 = __builtin_amdgcn_mfma_f32_16x16x32_bf16(a0, b, acc0, 0, 0, 0);
    acc1 = __builtin_amdgcn_mfma_f32_16x16x32_bf16(a1, b, acc1, 0, 0, 0);
  }
}

// gates tail: z -> LDS transpose -> sigmoid/tanh. c-state plain (same-thread
// mapping, block-private). h packed to 8B in LDS, stored coherent.
__device__ __forceinline__ void gates_store(float* zbuf, u16* hpk,
                                            int w, int lane, int quad, int l15,
                                            int m0, int tblk,
                                            const f32x4& acc0, const f32x4& acc1,
                                            const float* bias,
                                            const float* cin, float* cout,
                                            u16* hout, bool czero) {
#pragma unroll
  for (int r = 0; r < 4; ++r) {
    zbuf[(w * 32 + quad * 4 + r) * 17 + l15]      = acc0[r];
    zbuf[(w * 32 + 16 + quad * 4 + r) * 17 + l15] = acc1[r];
  }
  __syncthreads();
#pragma unroll
  for (int rep = 0; rep < 2; ++rep) {
    int pp = lane + rep * 64;
    int ml = pp >> 2;
    int cc = pp & 3;
    int col = tblk * 4 + cc;
    int zr = (w * 32 + ml) * 17;
    float iv = zbuf[zr + 0 + cc]  + bias[col];
    float fv = zbuf[zr + 4 + cc]  + bias[1024 + col];
    float gv = zbuf[zr + 8 + cc]  + bias[2048 + col];
    float ov = zbuf[zr + 12 + cc] + bias[3072 + col];
    size_t gi = (size_t)(m0 + ml) * NU + col;
    float cold = czero ? 0.f : cin[gi];
    float si = 1.f / (1.f + __expf(-iv));
    float sf = 1.f / (1.f + __expf(-fv));
    float so = 1.f / (1.f + __expf(-ov));
    float e2g = __expf(2.f * gv);
    float tg  = (e2g - 1.f) / (e2g + 1.f);
    float cn  = sf * cold + si * tg;
    float e2c = __expf(2.f * cn);
    float tc  = (e2c - 1.f) / (e2c + 1.f);
    cout[gi] = cn;
    hpk[w * 128 + ml * 4 + cc] = f2bf(so * tc);
  }
  __syncthreads();
  if (lane < 32) {
    union { u16 h4[4]; u64 q; } u;
#pragma unroll
    for (int c = 0; c < 4; ++c) u.h4[c] = hpk[w * 128 + lane * 4 + c];
    cstore64(hout + (size_t)(m0 + lane) * NU + tblk * 4, u.q);
  }
}

// dense head: blocks 0..127 own one batch row each. h via coherent loads.
__device__ void denseF(const P& p, float* dloc, int tid, int bid,
                       const u16* hsrc, int step) {
  if (bid < 128) {
    int m = bid;
    int j = tid >> 3, sub = tid & 7;
    float sum = 0.f;
    const u16* hr = hsrc + (size_t)m * NU + sub * 128;
#pragma unroll
    for (int i = 0; i < 16; ++i) {
      u64 a = cload64(hr + i * 8);
      u64 b = cload64(hr + i * 8 + 4);
      union { u64 q[2]; u16 h[8]; } u; u.q[0] = a; u.q[1] = b;
#pragma unroll
      for (int e = 0; e < 8; ++e)
        sum += bf2f(u.h[e]) * p.W1[(sub * 128 + i * 8 + e) * 32 + j];
    }
    sum += __shfl_down(sum, 4, 8);
    sum += __shfl_down(sum, 2, 8);
    sum += __shfl_down(sum, 1, 8);
    if (sub == 0) dloc[j] = fmaxf(sum + p.b1[j], 0.f);
    __syncthreads();
    if (tid < 64) {
      int f = tid;
      float s2 = p.b2[f];
#pragma unroll
      for (int k = 0; k < 32; ++k) s2 += dloc[k] * p.W2[k * 64 + f];
      p.out[((size_t)m * NOUT + step) * NF + f] = s2;
      cstoref(&p.pred[(size_t)m * NF + f], s2);
    }
  }
}

__global__ void __launch_bounds__(256) rnn_persist(P p) {
  __shared__ __align__(16) u16 Asb[32 * AS];   // 33,280 B
  __shared__ float zbuf[128 * 17];             //  8,704 B
  __shared__ u16 hpack[4 * 32 * 4];            //  1,024 B
  __shared__ float dloc[32];

  const int tid = threadIdx.x;
  const int bid = blockIdx.x;
  const int wgn = bid & 63;
  const int mg  = bid >> 6;
  const int m0  = mg * 32;
  const int w    = tid >> 6;
  const int lane = tid & 63;
  const int quad = lane >> 4;
  const int l15  = lane & 15;
  const int tblk = wgn * 4 + w;

  const u16* tbE = p.packE + (size_t)tblk * 17408;  // [x(2 units); h(32 units)]
  const u16* tbC = p.packC + (size_t)tblk * 17408;  // [pred(2); hl(32)]
  const u16* tbR = p.packR + (size_t)tblk * 32768;  // [hl(32); hr(32)]

  u32 bno = 0;

  // ---- encoder: 256 steps; phases: x(64) | h[0:512] | h[512:1024] ----
  for (int t = 0; t < NT; ++t) {
    const u16* hread = (t & 1) ? p.h1 : p.h0;
    u16* hwrite      = (t & 1) ? p.h0 : p.h1;
    f32x4 acc0 = {0.f, 0.f, 0.f, 0.f};
    f32x4 acc1 = {0.f, 0.f, 0.f, 0.f};
    stage_x64(Asb, tid, m0, p.x, t);
    __syncthreads();
    mfma_phase(acc0, acc1, Asb, tbE, 0, 2, l15, quad, lane);
    if (t > 0) {
      __syncthreads();
      stage512(Asb, tid, m0, hread, 0);
      __syncthreads();
      mfma_phase(acc0, acc1, Asb, tbE, 2, 16, l15, quad, lane);
      __syncthreads();
      stage512(Asb, tid, m0, hread, 512);
      __syncthreads();
      mfma_phase(acc0, acc1, Asb, tbE, 18, 16, l15, quad, lane);
    }
    gates_store(zbuf, hpack, w, lane, quad, l15, m0, tblk, acc0, acc1,
                p.bl, p.cE, p.cE, hwrite, t == 0);
    ++bno; gbar(p.bar, bno, bid, tid);
  }
  // final encoder h in p.h0

  denseF(p, dloc, tid, bid, p.h0, 0);
  ++bno; gbar(p.bar, bno, bid, tid);

  // ---- autoregressive: 31 steps (no copy phase: s==1 reads encoder state) ----
  for (int s = 1; s < NOUT; ++s) {
    const u16* hlr = (s == 1) ? p.h0 : ((s & 1) ? p.hl1 : p.hl0);
    u16*       hlw = (s & 1) ? p.hl0 : p.hl1;
    const u16* hrr = (s == 1) ? p.h0 : ((s & 1) ? p.hr1 : p.hr0);
    u16*       hrw = (s & 1) ? p.hr0 : p.hr1;
    const float* cinL = (s == 1) ? p.cE : p.cL;
    const float* cinR = (s == 1) ? p.cE : p.cR;

    // lstm_cell: phases pred(64) | hl[0:512] | hl[512:1024]
    {
      f32x4 acc0 = {0.f, 0.f, 0.f, 0.f};
      f32x4 acc1 = {0.f, 0.f, 0.f, 0.f};
      stage64p(Asb, tid, m0, p.pred);
      __syncthreads();
      mfma_phase(acc0, acc1, Asb, tbC, 0, 2, l15, quad, lane);
      __syncthreads();
      stage512(Asb, tid, m0, hlr, 0);
      __syncthreads();
      mfma_phase(acc0, acc1, Asb, tbC, 2, 16, l15, quad, lane);
      __syncthreads();
      stage512(Asb, tid, m0, hlr, 512);
      __syncthreads();
      mfma_phase(acc0, acc1, Asb, tbC, 18, 16, l15, quad, lane);
      gates_store(zbuf, hpack, w, lane, quad, l15, m0, tblk, acc0, acc1,
                  p.bc, cinL, p.cL, hlw, false);
    }
    ++bno; gbar(p.bar, bno, bid, tid);

    // rnn_cell: phases hl_new[0:512] | hl_new[512:] | hr[0:512] | hr[512:]
    {
      f32x4 acc0 = {0.f, 0.f, 0.f, 0.f};
      f32x4 acc1 = {0.f, 0.f, 0.f, 0.f};
#pragma unroll
      for (int ph = 0; ph < 4; ++ph) {
        const u16* src = (ph < 2) ? hlw : hrr;
        stage512(Asb, tid, m0, src, (ph & 1) * 512);
        __syncthreads();
        mfma_phase(acc0, acc1, Asb, tbR, ph * 16, 16, l15, quad, lane);
        __syncthreads();
      }
      gates_store(zbuf, hpack, w, lane, quad, l15, m0, tblk, acc0, acc1,
                  p.br, cinR, p.cR, hrw, false);
    }
    ++bno; gbar(p.bar, bno, bid, tid);

    denseF(p, dloc, tid, bid, hrw, s);
    ++bno; gbar(p.bar, bno, bid, tid);
  }
}

extern "C" void kernel_launch(void* const* d_in, const int* in_sizes, int n_in,
                              void* d_out, int out_size, void* d_ws, size_t ws_size,
                              hipStream_t stream) {
  const float* x  = (const float*)d_in[0];
  const float* Wl = (const float*)d_in[1];
  const float* Rl = (const float*)d_in[2];
  const float* bl = (const float*)d_in[3];
  const float* Wc = (const float*)d_in[4];
  const float* Rc = (const float*)d_in[5];
  const float* bc = (const float*)d_in[6];
  const float* Wr = (const float*)d_in[7];
  const float* Rr = (const float*)d_in[8];
  const float* br = (const float*)d_in[9];
  const float* W1 = (const float*)d_in[10];
  const float* b1 = (const float*)d_in[11];
  const float* W2 = (const float*)d_in[12];
  const float* b2 = (const float*)d_in[13];

  char* ws = (char*)d_ws;
  size_t off = 0;
  auto alloc = [&](size_t bytes) -> void* {
    void* r = ws + off;
    off += (bytes + 255) & ~(size_t)255;
    return r;
  };
  const size_t szPackE = (size_t)256 * 17408 * 2;  // 8,912,896
  const size_t szPackR = (size_t)256 * 32768 * 2;  // 16,777,216
  u16* packE = (u16*)alloc(szPackE);
  u16* packC = (u16*)alloc(szPackE);
  u16* packR = (u16*)alloc(szPackR);
  u16* h0  = (u16*)alloc(NB * NU * 2);
  u16* h1  = (u16*)alloc(NB * NU * 2);
  u16* hl0 = (u16*)alloc(NB * NU * 2);
  u16* hl1 = (u16*)alloc(NB * NU * 2);
  u16* hr0 = (u16*)alloc(NB * NU * 2);
  u16* hr1 = (u16*)alloc(NB * NU * 2);
  float* cE = (float*)alloc(NB * NU * 4);
  float* cL = (float*)alloc(NB * NU * 4);
  float* cR = (float*)alloc(NB * NU * 4);
  float* pred = (float*)alloc(NB * NF * 4);
  u32* bar  = (u32*)alloc((GO_IDX + 64) * 4);

  init_bar<<<dim3(33), dim3(256), 0, stream>>>(bar);
  pack_weights<<<dim3(128 * 17), dim3(256), 0, stream>>>(Wl, Rl, 64, 17, packE);
  pack_weights<<<dim3(128 * 17), dim3(256), 0, stream>>>(Wc, Rc, 64, 17, packC);
  pack_weights<<<dim3(128 * 32), dim3(256), 0, stream>>>(Wr, Rr, 1024, 32, packR);

  static P p;
  p.x = x;
  p.packE = packE; p.packC = packC; p.packR = packR;
  p.bl = bl; p.bc = bc; p.br = br;
  p.W1 = W1; p.b1 = b1; p.W2 = W2; p.b2 = b2;
  p.h0 = h0; p.h1 = h1; p.hl0 = hl0; p.hl1 = hl1; p.hr0 = hr0; p.hr1 = hr1;
  p.pred = pred;
  p.cE = cE; p.cL = cL; p.cR = cR;
  p.out = (float*)d_out;
  p.bar = bar;

  rnn_persist<<<dim3(NBLK), dim3(256), 0, stream>>>(p);
}

// Round 10
// 4549.632 us; speedup vs baseline: 6.0584x; 1.1587x over previous
//
#include <hip/hip_runtime.h>

typedef unsigned short u16;
typedef unsigned int u32;
typedef unsigned long long u64;
typedef short v8s __attribute__((ext_vector_type(8)));
typedef int v4i __attribute__((ext_vector_type(4)));
typedef float f32x4 __attribute__((ext_vector_type(4)));

#define NB 128
#define NU 1024
#define NF 64
#define NT 256
#define NOUT 32
#define NBLK 256
#define AS 520      // LDS A row stride in u16: 512 + 8 pad
#define FSTRIDE 32  // flag padding: 32 u32 = 128 B (one cacheline)
#define GO_OFF (NBLK * FSTRIDE)

__device__ __forceinline__ u16 f2bf(float f) {
  union { float f; u32 u; } v; v.f = f;
  u32 x = v.u;
  return (u16)((x + 0x7fffu + ((x >> 16) & 1u)) >> 16);
}
__device__ __forceinline__ float bf2f(u16 u) {
  union { u32 u; float f; } v; v.u = ((u32)u) << 16;
  return v.f;
}

// --- coherent (agent-scope, fence-free) access helpers ---
__device__ __forceinline__ u64 cload64(const u16* p) {
  return __hip_atomic_load((const u64*)(const void*)p, __ATOMIC_RELAXED,
                           __HIP_MEMORY_SCOPE_AGENT);
}
__device__ __forceinline__ void cstore64(u16* p, u64 v) {
  __hip_atomic_store((u64*)(void*)p, v, __ATOMIC_RELAXED, __HIP_MEMORY_SCOPE_AGENT);
}
__device__ __forceinline__ float cloadf(const float* p) {
  return __hip_atomic_load(p, __ATOMIC_RELAXED, __HIP_MEMORY_SCOPE_AGENT);
}
__device__ __forceinline__ void cstoref(float* p, float v) {
  __hip_atomic_store(p, v, __ATOMIC_RELAXED, __HIP_MEMORY_SCOPE_AGENT);
}
// 16B coherent load: sc0 sc1 bypasses non-coherent L1/L2 (coherence point),
// half the transactions of 2x 8B atomics. Result valid after s_waitcnt vmcnt(0).
__device__ __forceinline__ v4i cload128(const void* p) {
  v4i r;
  asm volatile("global_load_dwordx4 %0, %1, off sc0 sc1" : "=v"(r) : "v"(p) : "memory");
  return r;
}

// Fence-free grid barrier, contention-free release:
//  - all waves drain vmcnt (data stores at coherence point), block sync
//  - tid0 stores padded arrival flag
//  - block0: 256 threads poll 256 arrival lines in parallel, then each thread
//    stores one per-block go-line (single reader per line -> no L2 serialization)
//  - block b polls only go[b]
__device__ __forceinline__ void gbar(u32* bar, u32 gen, int bid, int tid) {
  asm volatile("s_waitcnt vmcnt(0)" ::: "memory");
  __syncthreads();
  if (tid == 0)
    __hip_atomic_store(&bar[bid * FSTRIDE], gen, __ATOMIC_RELAXED, __HIP_MEMORY_SCOPE_AGENT);
  u32* go = bar + GO_OFF;
  if (bid == 0) {
    u32 spin = 0;
    while (__hip_atomic_load(&bar[tid * FSTRIDE], __ATOMIC_RELAXED, __HIP_MEMORY_SCOPE_AGENT) < gen) {
      if (++spin > 50000000u) break;  // escape hatch
    }
    __syncthreads();  // all 256 arrivals observed by this block
    __hip_atomic_store(&go[tid * FSTRIDE], gen, __ATOMIC_RELAXED, __HIP_MEMORY_SCOPE_AGENT);
  } else if (tid == 0) {
    u32 spin = 0;
    while (__hip_atomic_load(&go[bid * FSTRIDE], __ATOMIC_RELAXED, __HIP_MEMORY_SCOPE_AGENT) < gen) {
      if (++spin > 50000000u) break;  // escape hatch
    }
  }
  __syncthreads();
  asm volatile("" ::: "memory");
}

__global__ void init_bar(u32* bar) {
  int i = blockIdx.x * 256 + threadIdx.x;
  if (i < 2 * NBLK * FSTRIDE) bar[i] = 0;
}

// Pack [top(ktop x 4096); R(1024 x 4096)] into MFMA-B-fragment-major bf16 with
// gate-permuted columns: z' col (t*16 + q*4 + c) <- orig col (q*1024 + t*4 + c).
__global__ void pack_weights(const float* __restrict__ top, const float* __restrict__ R,
                             int ktop, int nchunk, u16* __restrict__ dst) {
  int line = blockIdx.x * 256 + threadIdx.x;
  int l = line & 63;
  int rest = line >> 6;
  int s = rest & 1; rest >>= 1;
  int kk = rest % nchunk;
  int t  = rest / nchunk;
  if (t >= 256) return;
  int kbase = kk * 64 + s * 32 + (l >> 4) * 8;
  int col = ((l >> 2) & 3) * 1024 + t * 4 + (l & 3);
  v8s o;
#pragma unroll
  for (int j = 0; j < 8; ++j) {
    int k = kbase + j;
    float v = (k < ktop) ? top[(size_t)k * 4096 + col]
                         : R[(size_t)(k - ktop) * 4096 + col];
    o[j] = (short)f2bf(v);
  }
  *(v8s*)(void*)(dst + (size_t)line * 8) = o;
}

struct P {
  const float* x;
  const u16 *packE, *packC, *packR;
  const float *bl, *bc, *br, *W1, *b1, *W2, *b2;
  u16 *h0, *h1, *hl0, *hl1, *hr0, *hr1;
  float* pred;   // fp32, coherent
  float *cE, *cL, *cR;
  float* out;
  u32* bar;
};

// ---- staging: 16B coherent loads, all 8 in flight -> one latency ----
__device__ __forceinline__ void stage512(u16* Asb, int tid, int m0,
                                         const u16* src, int c0) {
  v4i t0, t1, t2, t3, t4, t5, t6, t7;
  {
    int idx = tid;
    t0 = cload128(src + (size_t)(m0 + (idx >> 6)) * NU + c0 + (idx & 63) * 8); idx += 256;
    t1 = cload128(src + (size_t)(m0 + (idx >> 6)) * NU + c0 + (idx & 63) * 8); idx += 256;
    t2 = cload128(src + (size_t)(m0 + (idx >> 6)) * NU + c0 + (idx & 63) * 8); idx += 256;
    t3 = cload128(src + (size_t)(m0 + (idx >> 6)) * NU + c0 + (idx & 63) * 8); idx += 256;
    t4 = cload128(src + (size_t)(m0 + (idx >> 6)) * NU + c0 + (idx & 63) * 8); idx += 256;
    t5 = cload128(src + (size_t)(m0 + (idx >> 6)) * NU + c0 + (idx & 63) * 8); idx += 256;
    t6 = cload128(src + (size_t)(m0 + (idx >> 6)) * NU + c0 + (idx & 63) * 8); idx += 256;
    t7 = cload128(src + (size_t)(m0 + (idx >> 6)) * NU + c0 + (idx & 63) * 8);
  }
  asm volatile("s_waitcnt vmcnt(0)" ::: "memory");
  {
    int idx = tid;
    *(v4i*)(void*)(Asb + (idx >> 6) * AS + (idx & 63) * 8) = t0; idx += 256;
    *(v4i*)(void*)(Asb + (idx >> 6) * AS + (idx & 63) * 8) = t1; idx += 256;
    *(v4i*)(void*)(Asb + (idx >> 6) * AS + (idx & 63) * 8) = t2; idx += 256;
    *(v4i*)(void*)(Asb + (idx >> 6) * AS + (idx & 63) * 8) = t3; idx += 256;
    *(v4i*)(void*)(Asb + (idx >> 6) * AS + (idx & 63) * 8) = t4; idx += 256;
    *(v4i*)(void*)(Asb + (idx >> 6) * AS + (idx & 63) * 8) = t5; idx += 256;
    *(v4i*)(void*)(Asb + (idx >> 6) * AS + (idx & 63) * 8) = t6; idx += 256;
    *(v4i*)(void*)(Asb + (idx >> 6) * AS + (idx & 63) * 8) = t7;
  }
}
__device__ __forceinline__ void stage64p(u16* Asb, int tid, int m0,
                                         const float* predf) {
#pragma unroll
  for (int i = 0; i < 4; ++i) {
    int idx = tid + i * 256;
    int ml = idx >> 5, dw = idx & 31;
    const float* sp = predf + (size_t)(m0 + ml) * NF + dw * 2;
    float f0 = cloadf(sp);
    float f1 = cloadf(sp + 1);
    u32 v = (u32)f2bf(f0) | ((u32)f2bf(f1) << 16);
    *(u32*)(void*)(Asb + ml * AS + dw * 2) = v;
  }
}
__device__ __forceinline__ void stage_x64(u16* Asb, int tid, int m0,
                                          const float* x, int t) {
#pragma unroll
  for (int i = 0; i < 4; ++i) {
    int idx = tid + i * 256;
    int ml = idx >> 5, dw = idx & 31;
    const float* sp = x + ((size_t)(m0 + ml) * NT + t) * NF + dw * 2;
    u32 v = (u32)f2bf(sp[0]) | ((u32)f2bf(sp[1]) << 16);
    *(u32*)(void*)(Asb + ml * AS + dw * 2) = v;
  }
}

// One MFMA phase: A from LDS, B chunks from global (plain, L2-resident).
__device__ __forceinline__ void mfma_phase(f32x4& acc0, f32x4& acc1,
                                           const u16* Asb, const u16* tb,
                                           int base_i, int n,
                                           int l15, int quad, int lane) {
#pragma unroll
  for (int j = 0; j < 16; ++j) {
    if (j >= n) break;
    v8s b  = *(const v8s*)(const void*)(tb + ((size_t)((base_i + j) * 64 + lane)) * 8);
    v8s a0 = *(const v8s*)(const void*)(Asb + l15 * AS + j * 32 + quad * 8);
    v8s a1 = *(const v8s*)(const void*)(Asb + (16 + l15) * AS + j * 32 + quad * 8);
    acc0 = __builtin_amdgcn_mfma_f32_16x16x32_bf16(a0, b, acc0, 0, 0, 0);
    acc1 = __builtin_amdgcn_mfma_f32_16x16x32_bf16(a1, b, acc1, 0, 0, 0);
  }
}

// gates tail: z -> LDS transpose -> sigmoid/tanh. c-state plain (same-thread
// mapping, block-private). h packed to 8B in LDS, stored coherent.
__device__ __forceinline__ void gates_store(float* zbuf, u16* hpk,
                                            int w, int lane, int quad, int l15,
                                            int m0, int tblk,
                                            const f32x4& acc0, const f32x4& acc1,
                                            const float* bias,
                                            const float* cin, float* cout,
                                            u16* hout, bool czero) {
#pragma unroll
  for (int r = 0; r < 4; ++r) {
    zbuf[(w * 32 + quad * 4 + r) * 17 + l15]      = acc0[r];
    zbuf[(w * 32 + 16 + quad * 4 + r) * 17 + l15] = acc1[r];
  }
  __syncthreads();
#pragma unroll
  for (int rep = 0; rep < 2; ++rep) {
    int pp = lane + rep * 64;
    int ml = pp >> 2;
    int cc = pp & 3;
    int col = tblk * 4 + cc;
    int zr = (w * 32 + ml) * 17;
    float iv = zbuf[zr + 0 + cc]  + bias[col];
    float fv = zbuf[zr + 4 + cc]  + bias[1024 + col];
    float gv = zbuf[zr + 8 + cc]  + bias[2048 + col];
    float ov = zbuf[zr + 12 + cc] + bias[3072 + col];
    size_t gi = (size_t)(m0 + ml) * NU + col;
    float cold = czero ? 0.f : cin[gi];
    float si = 1.f / (1.f + __expf(-iv));
    float sf = 1.f / (1.f + __expf(-fv));
    float so = 1.f / (1.f + __expf(-ov));
    float e2g = __expf(2.f * gv);
    float tg  = (e2g - 1.f) / (e2g + 1.f);
    float cn  = sf * cold + si * tg;
    float e2c = __expf(2.f * cn);
    float tc  = (e2c - 1.f) / (e2c + 1.f);
    cout[gi] = cn;
    hpk[w * 128 + ml * 4 + cc] = f2bf(so * tc);
  }
  __syncthreads();
  if (lane < 32) {
    union { u16 h4[4]; u64 q; } u;
#pragma unroll
    for (int c = 0; c < 4; ++c) u.h4[c] = hpk[w * 128 + lane * 4 + c];
    cstore64(hout + (size_t)(m0 + lane) * NU + tblk * 4, u.q);
  }
}

// dense head: blocks 0..127 own one batch row each. h via coherent loads.
__device__ void denseF(const P& p, float* dloc, int tid, int bid,
                       const u16* hsrc, int step) {
  if (bid < 128) {
    int m = bid;
    int j = tid >> 3, sub = tid & 7;
    float sum = 0.f;
    const u16* hr = hsrc + (size_t)m * NU + sub * 128;
#pragma unroll
    for (int i = 0; i < 16; ++i) {
      u64 a = cload64(hr + i * 8);
      u64 b = cload64(hr + i * 8 + 4);
      union { u64 q[2]; u16 h[8]; } u; u.q[0] = a; u.q[1] = b;
#pragma unroll
      for (int e = 0; e < 8; ++e)
        sum += bf2f(u.h[e]) * p.W1[(sub * 128 + i * 8 + e) * 32 + j];
    }
    sum += __shfl_down(sum, 4, 8);
    sum += __shfl_down(sum, 2, 8);
    sum += __shfl_down(sum, 1, 8);
    if (sub == 0) dloc[j] = fmaxf(sum + p.b1[j], 0.f);
    __syncthreads();
    if (tid < 64) {
      int f = tid;
      float s2 = p.b2[f];
#pragma unroll
      for (int k = 0; k < 32; ++k) s2 += dloc[k] * p.W2[k * 64 + f];
      p.out[((size_t)m * NOUT + step) * NF + f] = s2;
      cstoref(&p.pred[(size_t)m * NF + f], s2);
    }
  }
}

__global__ void __launch_bounds__(256) rnn_persist(P p) {
  __shared__ __align__(16) u16 Asb[32 * AS];   // 33,280 B
  __shared__ float zbuf[128 * 17];             //  8,704 B
  __shared__ u16 hpack[4 * 32 * 4];            //  1,024 B
  __shared__ float dloc[32];

  const int tid = threadIdx.x;
  const int bid = blockIdx.x;
  const int wgn = bid & 63;
  const int mg  = bid >> 6;
  const int m0  = mg * 32;
  const int w    = tid >> 6;
  const int lane = tid & 63;
  const int quad = lane >> 4;
  const int l15  = lane & 15;
  const int tblk = wgn * 4 + w;

  const u16* tbE = p.packE + (size_t)tblk * 17408;  // [x(2 units); h(32 units)]
  const u16* tbC = p.packC + (size_t)tblk * 17408;  // [pred(2); hl(32)]
  const u16* tbR = p.packR + (size_t)tblk * 32768;  // [hl(32); hr(32)]

  u32 bno = 0;

  // ---- encoder: 256 steps; phases: x(64) | h[0:512] | h[512:1024] ----
  for (int t = 0; t < NT; ++t) {
    const u16* hread = (t & 1) ? p.h1 : p.h0;
    u16* hwrite      = (t & 1) ? p.h0 : p.h1;
    f32x4 acc0 = {0.f, 0.f, 0.f, 0.f};
    f32x4 acc1 = {0.f, 0.f, 0.f, 0.f};
    stage_x64(Asb, tid, m0, p.x, t);
    __syncthreads();
    mfma_phase(acc0, acc1, Asb, tbE, 0, 2, l15, quad, lane);
    if (t > 0) {
      __syncthreads();
      stage512(Asb, tid, m0, hread, 0);
      __syncthreads();
      mfma_phase(acc0, acc1, Asb, tbE, 2, 16, l15, quad, lane);
      __syncthreads();
      stage512(Asb, tid, m0, hread, 512);
      __syncthreads();
      mfma_phase(acc0, acc1, Asb, tbE, 18, 16, l15, quad, lane);
    }
    gates_store(zbuf, hpack, w, lane, quad, l15, m0, tblk, acc0, acc1,
                p.bl, p.cE, p.cE, hwrite, t == 0);
    ++bno; gbar(p.bar, bno, bid, tid);
  }
  // final encoder h in p.h0

  denseF(p, dloc, tid, bid, p.h0, 0);
  ++bno; gbar(p.bar, bno, bid, tid);

  // ---- autoregressive: 31 steps (no copy phase: s==1 reads encoder state) ----
  for (int s = 1; s < NOUT; ++s) {
    const u16* hlr = (s == 1) ? p.h0 : ((s & 1) ? p.hl1 : p.hl0);
    u16*       hlw = (s & 1) ? p.hl0 : p.hl1;
    const u16* hrr = (s == 1) ? p.h0 : ((s & 1) ? p.hr1 : p.hr0);
    u16*       hrw = (s & 1) ? p.hr0 : p.hr1;
    const float* cinL = (s == 1) ? p.cE : p.cL;
    const float* cinR = (s == 1) ? p.cE : p.cR;

    // lstm_cell: phases pred(64) | hl[0:512] | hl[512:1024]
    {
      f32x4 acc0 = {0.f, 0.f, 0.f, 0.f};
      f32x4 acc1 = {0.f, 0.f, 0.f, 0.f};
      stage64p(Asb, tid, m0, p.pred);
      __syncthreads();
      mfma_phase(acc0, acc1, Asb, tbC, 0, 2, l15, quad, lane);
      __syncthreads();
      stage512(Asb, tid, m0, hlr, 0);
      __syncthreads();
      mfma_phase(acc0, acc1, Asb, tbC, 2, 16, l15, quad, lane);
      __syncthreads();
      stage512(Asb, tid, m0, hlr, 512);
      __syncthreads();
      mfma_phase(acc0, acc1, Asb, tbC, 18, 16, l15, quad, lane);
      gates_store(zbuf, hpack, w, lane, quad, l15, m0, tblk, acc0, acc1,
                  p.bc, cinL, p.cL, hlw, false);
    }
    ++bno; gbar(p.bar, bno, bid, tid);

    // rnn_cell: phases hl_new[0:512] | hl_new[512:] | hr[0:512] | hr[512:]
    {
      f32x4 acc0 = {0.f, 0.f, 0.f, 0.f};
      f32x4 acc1 = {0.f, 0.f, 0.f, 0.f};
#pragma unroll
      for (int ph = 0; ph < 4; ++ph) {
        const u16* src = (ph < 2) ? hlw : hrr;
        stage512(Asb, tid, m0, src, (ph & 1) * 512);
        __syncthreads();
        mfma_phase(acc0, acc1, Asb, tbR, ph * 16, 16, l15, quad, lane);
        __syncthreads();
      }
      gates_store(zbuf, hpack, w, lane, quad, l15, m0, tblk, acc0, acc1,
                  p.br, cinR, p.cR, hrw, false);
    }
    ++bno; gbar(p.bar, bno, bid, tid);

    denseF(p, dloc, tid, bid, hrw, s);
    ++bno; gbar(p.bar, bno, bid, tid);
  }
}

extern "C" void kernel_launch(void* const* d_in, const int* in_sizes, int n_in,
                              void* d_out, int out_size, void* d_ws, size_t ws_size,
                              hipStream_t stream) {
  const float* x  = (const float*)d_in[0];
  const float* Wl = (const float*)d_in[1];
  const float* Rl = (const float*)d_in[2];
  const float* bl = (const float*)d_in[3];
  const float* Wc = (const float*)d_in[4];
  const float* Rc = (const float*)d_in[5];
  const float* bc = (const float*)d_in[6];
  const float* Wr = (const float*)d_in[7];
  const float* Rr = (const float*)d_in[8];
  const float* br = (const float*)d_in[9];
  const float* W1 = (const float*)d_in[10];
  const float* b1 = (const float*)d_in[11];
  const float* W2 = (const float*)d_in[12];
  const float* b2 = (const float*)d_in[13];

  char* ws = (char*)d_ws;
  size_t off = 0;
  auto alloc = [&](size_t bytes) -> void* {
    void* r = ws + off;
    off += (bytes + 255) & ~(size_t)255;
    return r;
  };
  const size_t szPackE = (size_t)256 * 17408 * 2;  // 8,912,896
  const size_t szPackR = (size_t)256 * 32768 * 2;  // 16,777,216
  u16* packE = (u16*)alloc(szPackE);
  u16* packC = (u16*)alloc(szPackE);
  u16* packR = (u16*)alloc(szPackR);
  u16* h0  = (u16*)alloc(NB * NU * 2);
  u16* h1  = (u16*)alloc(NB * NU * 2);
  u16* hl0 = (u16*)alloc(NB * NU * 2);
  u16* hl1 = (u16*)alloc(NB * NU * 2);
  u16* hr0 = (u16*)alloc(NB * NU * 2);
  u16* hr1 = (u16*)alloc(NB * NU * 2);
  float* cE = (float*)alloc(NB * NU * 4);
  float* cL = (float*)alloc(NB * NU * 4);
  float* cR = (float*)alloc(NB * NU * 4);
  float* pred = (float*)alloc(NB * NF * 4);
  u32* bar  = (u32*)alloc(2 * NBLK * FSTRIDE * 4);

  init_bar<<<dim3(64), dim3(256), 0, stream>>>(bar);
  pack_weights<<<dim3(128 * 17), dim3(256), 0, stream>>>(Wl, Rl, 64, 17, packE);
  pack_weights<<<dim3(128 * 17), dim3(256), 0, stream>>>(Wc, Rc, 64, 17, packC);
  pack_weights<<<dim3(128 * 32), dim3(256), 0, stream>>>(Wr, Rr, 1024, 32, packR);

  static P p;
  p.x = x;
  p.packE = packE; p.packC = packC; p.packR = packR;
  p.bl = bl; p.bc = bc; p.br = br;
  p.W1 = W1; p.b1 = b1; p.W2 = W2; p.b2 = b2;
  p.h0 = h0; p.h1 = h1; p.hl0 = hl0; p.hl1 = hl1; p.hr0 = hr0; p.hr1 = hr1;
  p.pred = pred;
  p.cE = cE; p.cL = cL; p.cR = cR;
  p.out = (float*)d_out;
  p.bar = bar;

  rnn_persist<<<dim3(NBLK), dim3(256), 0, stream>>>(p);
}